// Round 1
// baseline (206662.085 us; speedup 1.0000x reference)
//
#include <hip/hip_runtime.h>
#include <stdint.h>

typedef unsigned short u16;
typedef unsigned int u32;

__device__ __forceinline__ float bf2f(u16 v) {
    return __uint_as_float(((u32)v) << 16);
}
__device__ __forceinline__ u16 f2bf(float f) {
    u32 u = __float_as_uint(f);
    u32 r = (u + 0x7fffu + ((u >> 16) & 1u)) >> 16;
    return (u16)r;
}

// ---------------- Kernel 1: BN statistics (cnt, sum, sumsq over active sites)
__global__ __launch_bounds__(256) void k_stats(const float* __restrict__ x, int n,
                                               float* __restrict__ stats) {
    int t = blockIdx.x * 256 + threadIdx.x;
    int stride = gridDim.x * 256;
    float c = 0.f, s = 0.f, ss = 0.f;
    for (int i = t; i < n; i += stride) {
        float v = x[i];
        if (v != 0.f) { c += 1.f; s += v; ss = fmaf(v, v, ss); }
    }
    for (int off = 32; off > 0; off >>= 1) {
        c  += __shfl_down(c, off);
        s  += __shfl_down(s, off);
        ss += __shfl_down(ss, off);
    }
    __shared__ float red[3][4];
    int lane = threadIdx.x & 63, wv = threadIdx.x >> 6;
    if (lane == 0) { red[0][wv] = c; red[1][wv] = s; red[2][wv] = ss; }
    __syncthreads();
    if (threadIdx.x == 0) {
        atomicAdd(&stats[0], red[0][0] + red[0][1] + red[0][2] + red[0][3]);
        atomicAdd(&stats[1], red[1][0] + red[1][1] + red[1][2] + red[1][3]);
        atomicAdd(&stats[2], red[2][0] + red[2][1] + red[2][2] + red[2][3]);
    }
}

// ---------------- Kernel 2: finalize BN affine -> scale/shift
__global__ void k_finalize(const float* __restrict__ g, const float* __restrict__ b,
                           float* __restrict__ stats) {
    float n = stats[0]; if (n < 1.f) n = 1.f;
    float mean = stats[1] / n;
    float var = stats[2] / n - mean * mean;
    if (var < 0.f) var = 0.f;
    float scale = g[0] * rsqrtf(var + 1e-5f);
    stats[4] = scale;
    stats[5] = b[0] - mean * scale;
}

// ---------------- Kernel 3: fused BN-apply + conv1(1->32)+ReLU + conv2(32->64)+ReLU + maxpool2x2
// One block per image. LDS: feat padded 30x30 f32, h1 padded 30x30x32 bf16, mask bytes.
__global__ __launch_bounds__(256) void k_conv(const float* __restrict__ x,
    const float* __restrict__ w1, const float* __restrict__ b1,
    const float* __restrict__ w2, const float* __restrict__ b2,
    const float* __restrict__ stats, u16* __restrict__ pooled)
{
    __shared__ float feat[30][30];
    __shared__ u16 h1[30][30][32];
    __shared__ unsigned char mk[784];
    const int t = threadIdx.x;
    const int b = blockIdx.x;
    const float scale = stats[4], shift = stats[5];

    // zero padded buffers
    for (int i = t; i < 900; i += 256) (&feat[0][0])[i] = 0.f;
    for (int i = t; i < 14400; i += 256) ((u32*)h1)[i] = 0u;
    __syncthreads();

    // load x, compute mask + BN-applied features
    const float* xb = x + (size_t)b * 784;
    for (int i = t; i < 784; i += 256) {
        float v = xb[i];
        bool m = (v != 0.f);
        mk[i] = m ? 1 : 0;
        int h = i / 28, w = i - h * 28;
        feat[h + 1][w + 1] = m ? fmaf(v, scale, shift) : 0.f;
    }
    __syncthreads();

    // conv1: co = t%32, pixel-group = t/32 (8 groups)
    {
        const int co = t & 31, pxg = t >> 5;
        float wk[9];
        #pragma unroll
        for (int j = 0; j < 9; ++j) wk[j] = w1[j * 32 + co];
        const float bias = b1[co];
        for (int px = pxg; px < 784; px += 8) {
            if (!mk[px]) continue;  // h1 stays zero
            int h = px / 28, w = px - h * 28;
            float acc = bias;
            #pragma unroll
            for (int kh = 0; kh < 3; ++kh)
                #pragma unroll
                for (int kw = 0; kw < 3; ++kw)
                    acc = fmaf(feat[h + kh][w + kw], wk[kh * 3 + kw], acc);
            h1[h + 1][w + 1][co] = f2bf(fmaxf(acc, 0.f));
        }
    }
    __syncthreads();

    // conv2 + bias + mask + ReLU + 2x2 maxpool
    {
        const int co_b = (t & 15) * 4;   // 16 groups of 4 output channels
        const int pg = t >> 4;           // 16 pixel groups
        const float4 b2v4 = *(const float4*)(b2 + co_b);
        const float bb[4] = { b2v4.x, b2v4.y, b2v4.z, b2v4.w };
        for (int ppi = pg; ppi < 98; ppi += 16) {
            const int pp0 = 2 * ppi;                  // pooled pixel index (even)
            const int ph0 = pp0 / 14, pw0 = pp0 - ph0 * 14;
            const int hs = 2 * ph0, ws = 2 * pw0;     // source patch origin (2 rows x 4 cols)
            float acc[8][4];
            #pragma unroll
            for (int s = 0; s < 8; ++s)
                #pragma unroll
                for (int c = 0; c < 4; ++c) acc[s][c] = 0.f;

            #pragma unroll
            for (int tap = 0; tap < 9; ++tap) {
                const int kh = tap / 3, kw = tap - kh * 3;
                const u16* hp = &h1[hs + kh][ws + kw][0];
                const float* wp = w2 + (size_t)(tap * 32) * 64 + co_b;
                for (int c4 = 0; c4 < 8; ++c4) {
                    const float4 wv0 = *(const float4*)(wp + (c4 * 4 + 0) * 64);
                    const float4 wv1 = *(const float4*)(wp + (c4 * 4 + 1) * 64);
                    const float4 wv2 = *(const float4*)(wp + (c4 * 4 + 2) * 64);
                    const float4 wv3 = *(const float4*)(wp + (c4 * 4 + 3) * 64);
                    #pragma unroll
                    for (int dy = 0; dy < 2; ++dy) {
                        #pragma unroll
                        for (int dx = 0; dx < 4; ++dx) {
                            uint2 av = *(const uint2*)(hp + dy * 960 + dx * 32 + c4 * 4);
                            float a0 = __uint_as_float(av.x << 16);
                            float a1 = __uint_as_float(av.x & 0xffff0000u);
                            float a2 = __uint_as_float(av.y << 16);
                            float a3 = __uint_as_float(av.y & 0xffff0000u);
                            float* a = acc[dy * 4 + dx];
                            a[0] = fmaf(a0, wv0.x, a[0]);
                            a[1] = fmaf(a0, wv0.y, a[1]);
                            a[2] = fmaf(a0, wv0.z, a[2]);
                            a[3] = fmaf(a0, wv0.w, a[3]);
                            a[0] = fmaf(a1, wv1.x, a[0]);
                            a[1] = fmaf(a1, wv1.y, a[1]);
                            a[2] = fmaf(a1, wv1.z, a[2]);
                            a[3] = fmaf(a1, wv1.w, a[3]);
                            a[0] = fmaf(a2, wv2.x, a[0]);
                            a[1] = fmaf(a2, wv2.y, a[1]);
                            a[2] = fmaf(a2, wv2.z, a[2]);
                            a[3] = fmaf(a2, wv2.w, a[3]);
                            a[0] = fmaf(a3, wv3.x, a[0]);
                            a[1] = fmaf(a3, wv3.y, a[1]);
                            a[2] = fmaf(a3, wv3.z, a[2]);
                            a[3] = fmaf(a3, wv3.w, a[3]);
                        }
                    }
                }
            }
            // pool (all values >= 0; inactive -> 0) and store bf16, NCHW-flat layout
            #pragma unroll
            for (int c = 0; c < 4; ++c) {
                float best0 = 0.f, best1 = 0.f;
                #pragma unroll
                for (int dy = 0; dy < 2; ++dy) {
                    #pragma unroll
                    for (int dx = 0; dx < 4; ++dx) {
                        bool mm = mk[(hs + dy) * 28 + ws + dx] != 0;
                        float val = mm ? fmaxf(acc[dy * 4 + dx][c] + bb[c], 0.f) : 0.f;
                        if (dx < 2) best0 = fmaxf(best0, val);
                        else        best1 = fmaxf(best1, val);
                    }
                }
                u32 pk = (u32)f2bf(best0) | ((u32)f2bf(best1) << 16);
                *(u32*)&pooled[(size_t)b * 12544 + (co_b + c) * 196 + pp0] = pk;
            }
        }
    }
}

// ---------------- Kernel 4: FC1 GEMM  out[n][m] (+=) = sum_k pooled[m][k]*fcw1[n][k]
// M-tile 64, N full 128, split-K 8; fp32 atomics into transposed fc1T [128][M].
__global__ __launch_bounds__(256) void k_fc1(const u16* __restrict__ pooled,
    const float* __restrict__ fcw1, float* __restrict__ fc1T, int M)
{
    __shared__ float As[32][64];
    __shared__ float Bs[32][128];
    const int t = threadIdx.x;
    const int m0 = blockIdx.x * 64;
    const int kc = blockIdx.y * 1568;
    const int tm = (t & 7) * 8;
    const int tn = (t >> 3) * 4;
    float acc[8][4];
    #pragma unroll
    for (int i = 0; i < 8; ++i)
        #pragma unroll
        for (int j = 0; j < 4; ++j) acc[i][j] = 0.f;

    for (int ks = kc; ks < kc + 1568; ks += 32) {
        __syncthreads();
        #pragma unroll
        for (int r = 0; r < 2; ++r) {  // stage A: 64m x 32k bf16
            int u = t + r * 256;
            int m = u >> 3, k4 = (u & 7) * 4;
            uint2 av = *(const uint2*)(pooled + (size_t)(m0 + m) * 12544 + ks + k4);
            As[k4 + 0][m] = __uint_as_float(av.x << 16);
            As[k4 + 1][m] = __uint_as_float(av.x & 0xffff0000u);
            As[k4 + 2][m] = __uint_as_float(av.y << 16);
            As[k4 + 3][m] = __uint_as_float(av.y & 0xffff0000u);
        }
        #pragma unroll
        for (int r = 0; r < 4; ++r) {  // stage B: 128n x 32k f32
            int u = t + r * 256;
            int n = u >> 3, k4 = (u & 7) * 4;
            float4 bv = *(const float4*)(fcw1 + (size_t)n * 12544 + ks + k4);
            Bs[k4 + 0][n] = bv.x; Bs[k4 + 1][n] = bv.y;
            Bs[k4 + 2][n] = bv.z; Bs[k4 + 3][n] = bv.w;
        }
        __syncthreads();
        #pragma unroll 8
        for (int k = 0; k < 32; ++k) {
            float4 a0 = *(const float4*)&As[k][tm];
            float4 a1 = *(const float4*)&As[k][tm + 4];
            float4 bv = *(const float4*)&Bs[k][tn];
            float av[8] = { a0.x, a0.y, a0.z, a0.w, a1.x, a1.y, a1.z, a1.w };
            float bw[4] = { bv.x, bv.y, bv.z, bv.w };
            #pragma unroll
            for (int i = 0; i < 8; ++i)
                #pragma unroll
                for (int j = 0; j < 4; ++j)
                    acc[i][j] = fmaf(av[i], bw[j], acc[i][j]);
        }
    }
    #pragma unroll
    for (int i = 0; i < 8; ++i)
        #pragma unroll
        for (int j = 0; j < 4; ++j)
            atomicAdd(&fc1T[(size_t)(tn + j) * M + m0 + tm + i], acc[i][j]);
}

// ---------------- Kernel 5: bias+ReLU + FC2 + log_softmax
__global__ __launch_bounds__(256) void k_fc2(const float* __restrict__ fc1T,
    const float* __restrict__ fcb1, const float* __restrict__ fcw2,
    const float* __restrict__ fcb2, float* __restrict__ out, int M)
{
    int m = blockIdx.x * 256 + threadIdx.x;
    if (m >= M) return;
    float acc[10];
    #pragma unroll
    for (int c = 0; c < 10; ++c) acc[c] = fcb2[c];
    for (int k = 0; k < 128; ++k) {
        float v = fmaxf(fc1T[(size_t)k * M + m] + fcb1[k], 0.f);
        #pragma unroll
        for (int c = 0; c < 10; ++c) acc[c] = fmaf(v, fcw2[c * 128 + k], acc[c]);
    }
    float mx = acc[0];
    #pragma unroll
    for (int c = 1; c < 10; ++c) mx = fmaxf(mx, acc[c]);
    float se = 0.f;
    #pragma unroll
    for (int c = 0; c < 10; ++c) se += expf(acc[c] - mx);
    float lse = mx + logf(se);
    #pragma unroll
    for (int c = 0; c < 10; ++c) out[(size_t)m * 10 + c] = acc[c] - lse;
}

extern "C" void kernel_launch(void* const* d_in, const int* in_sizes, int n_in,
                              void* d_out, int out_size, void* d_ws, size_t ws_size,
                              hipStream_t stream) {
    const float* x     = (const float*)d_in[0];
    const float* gamma = (const float*)d_in[1];
    const float* beta  = (const float*)d_in[2];
    const float* w1    = (const float*)d_in[3];
    const float* b1    = (const float*)d_in[4];
    const float* w2    = (const float*)d_in[5];
    const float* b2    = (const float*)d_in[6];
    const float* fcw1  = (const float*)d_in[7];
    const float* fcb1  = (const float*)d_in[8];
    const float* fcw2  = (const float*)d_in[9];
    const float* fcb2  = (const float*)d_in[10];
    float* out = (float*)d_out;

    const int B = in_sizes[0] / 784;  // 4096

    float* stats = (float*)d_ws;
    float* fc1T  = (float*)((char*)d_ws + 256);
    u16*   pooled = (u16*)((char*)d_ws + 256 + (size_t)128 * B * 4);

    hipMemsetAsync(stats, 0, 32, stream);
    hipMemsetAsync(fc1T, 0, (size_t)128 * B * 4, stream);

    k_stats<<<1024, 256, 0, stream>>>(x, B * 784, stats);
    k_finalize<<<1, 1, 0, stream>>>(gamma, beta, stats);
    k_conv<<<B, 256, 0, stream>>>(x, w1, b1, w2, b2, stats, pooled);
    k_fc1<<<dim3(B / 64, 8), 256, 0, stream>>>(pooled, fcw1, fc1T, B);
    k_fc2<<<B / 256, 256, 0, stream>>>(fc1T, fcb1, fcw2, fcb2, out, B);
}

// Round 2
// 676.053 us; speedup vs baseline: 305.6892x; 305.6892x over previous
//
#include <hip/hip_runtime.h>
#include <stdint.h>

typedef unsigned short u16;
typedef unsigned int u32;
typedef __attribute__((ext_vector_type(8))) short bf16x8;
typedef __attribute__((ext_vector_type(4))) float f32x4;

__device__ __forceinline__ u16 f2bf(float f) {
    u32 u = __float_as_uint(f);
    u32 r = (u + 0x7fffu + ((u >> 16) & 1u)) >> 16;
    return (u16)r;
}

// ---------------- Kernel 1: BN statistics (cnt, sum, sumsq over active sites)
__global__ __launch_bounds__(256) void k_stats(const float* __restrict__ x, int n,
                                               float* __restrict__ stats) {
    int t = blockIdx.x * 256 + threadIdx.x;
    int stride = gridDim.x * 256;
    float c = 0.f, s = 0.f, ss = 0.f;
    for (int i = t; i < n; i += stride) {
        float v = x[i];
        if (v != 0.f) { c += 1.f; s += v; ss = fmaf(v, v, ss); }
    }
    for (int off = 32; off > 0; off >>= 1) {
        c  += __shfl_down(c, off);
        s  += __shfl_down(s, off);
        ss += __shfl_down(ss, off);
    }
    __shared__ float red[3][4];
    int lane = threadIdx.x & 63, wv = threadIdx.x >> 6;
    if (lane == 0) { red[0][wv] = c; red[1][wv] = s; red[2][wv] = ss; }
    __syncthreads();
    if (threadIdx.x == 0) {
        atomicAdd(&stats[0], red[0][0] + red[0][1] + red[0][2] + red[0][3]);
        atomicAdd(&stats[1], red[1][0] + red[1][1] + red[1][2] + red[1][3]);
        atomicAdd(&stats[2], red[2][0] + red[2][1] + red[2][2] + red[2][3]);
    }
}

// ---------------- Kernel 2: finalize BN affine -> scale/shift
__global__ void k_finalize(const float* __restrict__ g, const float* __restrict__ b,
                           float* __restrict__ stats) {
    float n = stats[0]; if (n < 1.f) n = 1.f;
    float mean = stats[1] / n;
    float var = stats[2] / n - mean * mean;
    if (var < 0.f) var = 0.f;
    float scale = g[0] * rsqrtf(var + 1e-5f);
    stats[4] = scale;
    stats[5] = b[0] - mean * scale;
}

// ---------------- Kernel 2b: transpose w2 HWIO [tap][ci][co] -> w2b[tap][co][ci] bf16
__global__ __launch_bounds__(256) void k_prep(const float* __restrict__ w2,
                                              u16* __restrict__ w2b) {
    int i = blockIdx.x * 256 + threadIdx.x;
    if (i < 9 * 64 * 32) {
        int tap = i >> 11, rem = i & 2047, co = rem >> 5, ci = rem & 31;
        w2b[i] = f2bf(w2[tap * 2048 + ci * 64 + co]);
    }
}

// ---------------- Kernel 3: fused BN-apply + conv1 (VALU) + conv2 (MFMA) + pool
// One block (4 waves) per image.
// LDS h1 layout: [g=ch/8][py=h30*30+w30][ch%8] bf16 -> A-frag = 1 aligned ds_read_b128.
// M-tile remap: tile mt=(r,cg) covers pixels rows {2r,2r+1} x cols {8cg..8cg+7};
// m-index within tile = win*4 + dy*2 + dx  => D lane-group lg holds exactly window lg.
__global__ __launch_bounds__(256, 2) void k_conv(const float* __restrict__ x,
    const float* __restrict__ w1, const float* __restrict__ b1,
    const u16* __restrict__ w2b, const float* __restrict__ b2,
    const float* __restrict__ stats, u16* __restrict__ pooled)
{
    __shared__ u16 h1[28800];          // 4 * 900 * 8, 57600 B
    __shared__ float feat[30][30];
    __shared__ unsigned char mk[784];
    const int t = threadIdx.x;
    const int b = blockIdx.x;
    const int lane = t & 63;
    const int wv = t >> 6;             // wave id 0..3
    const int lg = lane >> 4;          // k-group / D-row-group / pool window
    const int lr = lane & 15;          // A row (pixel m) / B,D col

    // B fragments in registers for all 9 taps x 4 co-tiles (static indexing only)
    bf16x8 wf[9][4];
    #pragma unroll
    for (int tap = 0; tap < 9; ++tap)
        #pragma unroll
        for (int nt = 0; nt < 4; ++nt)
            wf[tap][nt] = *(const bf16x8*)(w2b + tap * 2048 + (nt * 16 + lr) * 32 + lg * 8);
    float bias2[4];
    #pragma unroll
    for (int nt = 0; nt < 4; ++nt) bias2[nt] = b2[nt * 16 + lr];

    const float scale = stats[4], shift = stats[5];

    for (int i = t; i < 14400; i += 256) ((u32*)h1)[i] = 0u;
    for (int i = t; i < 900; i += 256) (&feat[0][0])[i] = 0.f;
    __syncthreads();

    const float* xb = x + (size_t)b * 784;
    for (int i = t; i < 784; i += 256) {
        float v = xb[i];
        bool m = (v != 0.f);
        mk[i] = m ? 1 : 0;
        int h = i / 28, w = i - h * 28;
        feat[h + 1][w + 1] = m ? fmaf(v, scale, shift) : 0.f;
    }
    __syncthreads();

    // conv1: 2 output channels per thread, 16 pixel groups
    {
        const int cp = t & 15, pxg = t >> 4;
        float wk0[9], wk1[9];
        const float bs0 = b1[2 * cp], bs1 = b1[2 * cp + 1];
        #pragma unroll
        for (int j = 0; j < 9; ++j) {
            wk0[j] = w1[j * 32 + 2 * cp];
            wk1[j] = w1[j * 32 + 2 * cp + 1];
        }
        const int hslot = (cp >> 2) * 7200 + (cp & 3) * 2;
        for (int px = pxg; px < 784; px += 16) {
            if (!mk[px]) continue;      // inactive -> h1 stays zero
            int h = px / 28, w = px - h * 28;
            float a0 = bs0, a1 = bs1;
            #pragma unroll
            for (int kh = 0; kh < 3; ++kh)
                #pragma unroll
                for (int kw = 0; kw < 3; ++kw) {
                    float f = feat[h + kh][w + kw];
                    a0 = fmaf(f, wk0[kh * 3 + kw], a0);
                    a1 = fmaf(f, wk1[kh * 3 + kw], a1);
                }
            u32 pk = (u32)f2bf(fmaxf(a0, 0.f)) | ((u32)f2bf(fmaxf(a1, 0.f)) << 16);
            *(u32*)&h1[hslot + ((h + 1) * 30 + (w + 1)) * 8] = pk;
        }
    }
    __syncthreads();

    // conv2 (MFMA) + bias + mask + ReLU + 2x2 maxpool
    const int win = lr >> 2, dyl = (lr >> 1) & 1, dxl = lr & 1;
    const f32x4 zero4 = {0.f, 0.f, 0.f, 0.f};
    for (int mt = wv; mt < 56; mt += 4) {
        const int r = mt >> 2, cg = mt & 3;
        const int ih = 2 * r + dyl;
        int iw = 2 * (cg * 4 + win) + dxl;
        if (iw > 27) iw = 27;           // clamp padded lanes (their D rows are discarded)
        const char* abase = (const char*)h1 + lg * 14400 + (ih * 30 + iw) * 16;

        f32x4 acc[4];
        #pragma unroll
        for (int nt = 0; nt < 4; ++nt) acc[nt] = zero4;

        #pragma unroll
        for (int tap = 0; tap < 9; ++tap) {
            const int kh = tap / 3, kw = tap - kh * 3;
            bf16x8 af = *(const bf16x8*)(abase + (kh * 30 + kw) * 16);
            #pragma unroll
            for (int nt = 0; nt < 4; ++nt)
                acc[nt] = __builtin_amdgcn_mfma_f32_16x16x32_bf16(af, wf[tap][nt], acc[nt], 0, 0, 0);
        }

        const int pc = cg * 4 + lg;     // pooled column
        if (pc < 14) {
            const int m00 = mk[(2 * r) * 28 + 2 * pc];
            const int m01 = mk[(2 * r) * 28 + 2 * pc + 1];
            const int m10 = mk[(2 * r + 1) * 28 + 2 * pc];
            const int m11 = mk[(2 * r + 1) * 28 + 2 * pc + 1];
            #pragma unroll
            for (int nt = 0; nt < 4; ++nt) {
                float v0 = m00 ? fmaxf(acc[nt][0] + bias2[nt], 0.f) : 0.f;
                float v1 = m01 ? fmaxf(acc[nt][1] + bias2[nt], 0.f) : 0.f;
                float v2 = m10 ? fmaxf(acc[nt][2] + bias2[nt], 0.f) : 0.f;
                float v3 = m11 ? fmaxf(acc[nt][3] + bias2[nt], 0.f) : 0.f;
                float best = fmaxf(fmaxf(v0, v1), fmaxf(v2, v3));
                pooled[(size_t)b * 12544 + (nt * 16 + lr) * 196 + r * 14 + pc] = f2bf(best);
            }
        }
    }
}

// ---------------- Kernel 4: FC1 GEMM  out[n][m] (+=) = sum_k pooled[m][k]*fcw1[n][k]
__global__ __launch_bounds__(256) void k_fc1(const u16* __restrict__ pooled,
    const float* __restrict__ fcw1, float* __restrict__ fc1T, int M)
{
    __shared__ float As[32][64];
    __shared__ float Bs[32][128];
    const int t = threadIdx.x;
    const int m0 = blockIdx.x * 64;
    const int kc = blockIdx.y * 1568;
    const int tm = (t & 7) * 8;
    const int tn = (t >> 3) * 4;
    float acc[8][4];
    #pragma unroll
    for (int i = 0; i < 8; ++i)
        #pragma unroll
        for (int j = 0; j < 4; ++j) acc[i][j] = 0.f;

    for (int ks = kc; ks < kc + 1568; ks += 32) {
        __syncthreads();
        #pragma unroll
        for (int r = 0; r < 2; ++r) {
            int u = t + r * 256;
            int m = u >> 3, k4 = (u & 7) * 4;
            uint2 av = *(const uint2*)(pooled + (size_t)(m0 + m) * 12544 + ks + k4);
            As[k4 + 0][m] = __uint_as_float(av.x << 16);
            As[k4 + 1][m] = __uint_as_float(av.x & 0xffff0000u);
            As[k4 + 2][m] = __uint_as_float(av.y << 16);
            As[k4 + 3][m] = __uint_as_float(av.y & 0xffff0000u);
        }
        #pragma unroll
        for (int r = 0; r < 4; ++r) {
            int u = t + r * 256;
            int n = u >> 3, k4 = (u & 7) * 4;
            float4 bv = *(const float4*)(fcw1 + (size_t)n * 12544 + ks + k4);
            Bs[k4 + 0][n] = bv.x; Bs[k4 + 1][n] = bv.y;
            Bs[k4 + 2][n] = bv.z; Bs[k4 + 3][n] = bv.w;
        }
        __syncthreads();
        #pragma unroll 8
        for (int k = 0; k < 32; ++k) {
            float4 a0 = *(const float4*)&As[k][tm];
            float4 a1 = *(const float4*)&As[k][tm + 4];
            float4 bv = *(const float4*)&Bs[k][tn];
            float av[8] = { a0.x, a0.y, a0.z, a0.w, a1.x, a1.y, a1.z, a1.w };
            float bw[4] = { bv.x, bv.y, bv.z, bv.w };
            #pragma unroll
            for (int i = 0; i < 8; ++i)
                #pragma unroll
                for (int j = 0; j < 4; ++j)
                    acc[i][j] = fmaf(av[i], bw[j], acc[i][j]);
        }
    }
    #pragma unroll
    for (int i = 0; i < 8; ++i)
        #pragma unroll
        for (int j = 0; j < 4; ++j)
            atomicAdd(&fc1T[(size_t)(tn + j) * M + m0 + tm + i], acc[i][j]);
}

// ---------------- Kernel 5: bias+ReLU + FC2 + log_softmax
__global__ __launch_bounds__(256) void k_fc2(const float* __restrict__ fc1T,
    const float* __restrict__ fcb1, const float* __restrict__ fcw2,
    const float* __restrict__ fcb2, float* __restrict__ out, int M)
{
    int m = blockIdx.x * 256 + threadIdx.x;
    if (m >= M) return;
    float acc[10];
    #pragma unroll
    for (int c = 0; c < 10; ++c) acc[c] = fcb2[c];
    for (int k = 0; k < 128; ++k) {
        float v = fmaxf(fc1T[(size_t)k * M + m] + fcb1[k], 0.f);
        #pragma unroll
        for (int c = 0; c < 10; ++c) acc[c] = fmaf(v, fcw2[c * 128 + k], acc[c]);
    }
    float mx = acc[0];
    #pragma unroll
    for (int c = 1; c < 10; ++c) mx = fmaxf(mx, acc[c]);
    float se = 0.f;
    #pragma unroll
    for (int c = 0; c < 10; ++c) se += expf(acc[c] - mx);
    float lse = mx + logf(se);
    #pragma unroll
    for (int c = 0; c < 10; ++c) out[(size_t)m * 10 + c] = acc[c] - lse;
}

extern "C" void kernel_launch(void* const* d_in, const int* in_sizes, int n_in,
                              void* d_out, int out_size, void* d_ws, size_t ws_size,
                              hipStream_t stream) {
    const float* x     = (const float*)d_in[0];
    const float* gamma = (const float*)d_in[1];
    const float* beta  = (const float*)d_in[2];
    const float* w1    = (const float*)d_in[3];
    const float* b1    = (const float*)d_in[4];
    const float* w2    = (const float*)d_in[5];
    const float* b2    = (const float*)d_in[6];
    const float* fcw1  = (const float*)d_in[7];
    const float* fcb1  = (const float*)d_in[8];
    const float* fcw2  = (const float*)d_in[9];
    const float* fcb2  = (const float*)d_in[10];
    float* out = (float*)d_out;

    const int B = in_sizes[0] / 784;  // 4096

    float* stats = (float*)d_ws;
    // w2b aliases the fc1T region: used by k_prep/k_conv, then overwritten by the
    // fc1T memset AFTER k_conv (stream-ordered) -> zero extra workspace.
    u16*   w2b   = (u16*)((char*)d_ws + 256);
    float* fc1T  = (float*)((char*)d_ws + 256);
    u16*   pooled = (u16*)((char*)d_ws + 256 + (size_t)128 * B * 4);

    hipMemsetAsync(stats, 0, 32, stream);
    k_stats<<<1024, 256, 0, stream>>>(x, B * 784, stats);
    k_finalize<<<1, 1, 0, stream>>>(gamma, beta, stats);
    k_prep<<<72, 256, 0, stream>>>(w2, w2b);
    k_conv<<<B, 256, 0, stream>>>(x, w1, b1, w2b, b2, stats, pooled);
    hipMemsetAsync(fc1T, 0, (size_t)128 * B * 4, stream);
    k_fc1<<<dim3(B / 64, 8), 256, 0, stream>>>(pooled, fcw1, fc1T, B);
    k_fc2<<<B / 256, 256, 0, stream>>>(fc1T, fcb1, fcw2, fcb2, out, B);
}

// Round 4
// 399.697 us; speedup vs baseline: 517.0463x; 1.6914x over previous
//
#include <hip/hip_runtime.h>
#include <stdint.h>

typedef unsigned short u16;
typedef unsigned int u32;
typedef __attribute__((ext_vector_type(8))) short bf16x8;
typedef __attribute__((ext_vector_type(4))) float f32x4;

__device__ __forceinline__ u16 f2bf(float f) {
    u32 u = __float_as_uint(f);
    u32 r = (u + 0x7fffu + ((u >> 16) & 1u)) >> 16;
    return (u16)r;
}

__device__ __forceinline__ void gload16(const u16* src, u16* dst) {
    __builtin_amdgcn_global_load_lds(
        (const __attribute__((address_space(1))) u32*)src,
        (__attribute__((address_space(3))) u32*)dst, 16, 0, 0);
}

// ---------------- Kernel 1: BN statistics
__global__ __launch_bounds__(256) void k_stats(const float* __restrict__ x, int n,
                                               float* __restrict__ stats) {
    int t = blockIdx.x * 256 + threadIdx.x;
    int stride = gridDim.x * 256;
    float c = 0.f, s = 0.f, ss = 0.f;
    for (int i = t; i < n; i += stride) {
        float v = x[i];
        if (v != 0.f) { c += 1.f; s += v; ss = fmaf(v, v, ss); }
    }
    for (int off = 32; off > 0; off >>= 1) {
        c  += __shfl_down(c, off);
        s  += __shfl_down(s, off);
        ss += __shfl_down(ss, off);
    }
    __shared__ float red[3][4];
    int lane = threadIdx.x & 63, wv = threadIdx.x >> 6;
    if (lane == 0) { red[0][wv] = c; red[1][wv] = s; red[2][wv] = ss; }
    __syncthreads();
    if (threadIdx.x == 0) {
        atomicAdd(&stats[0], red[0][0] + red[0][1] + red[0][2] + red[0][3]);
        atomicAdd(&stats[1], red[1][0] + red[1][1] + red[1][2] + red[1][3]);
        atomicAdd(&stats[2], red[2][0] + red[2][1] + red[2][2] + red[2][3]);
    }
}

// ---------------- Kernel 2: finalize BN affine
__global__ void k_finalize(const float* __restrict__ g, const float* __restrict__ b,
                           float* __restrict__ stats) {
    float n = stats[0]; if (n < 1.f) n = 1.f;
    float mean = stats[1] / n;
    float var = stats[2] / n - mean * mean;
    if (var < 0.f) var = 0.f;
    float scale = g[0] * rsqrtf(var + 1e-5f);
    stats[4] = scale;
    stats[5] = b[0] - mean * scale;
}

// ---------------- Kernel 2b: w2 HWIO -> w2b[tap][co][ci] bf16
__global__ __launch_bounds__(256) void k_prep(const float* __restrict__ w2,
                                              u16* __restrict__ w2b) {
    int i = blockIdx.x * 256 + threadIdx.x;
    if (i < 9 * 64 * 32) {
        int tap = i >> 11, rem = i & 2047, co = rem >> 5, ci = rem & 31;
        w2b[i] = f2bf(w2[tap * 2048 + ci * 64 + co]);
    }
}

// ---------------- Kernel 2c: fcw1 f32 -> bf16 (same [n][k] layout)
__global__ __launch_bounds__(256) void k_prepw(const float* __restrict__ fcw1,
                                               u16* __restrict__ fcw1b, int n) {
    int i = blockIdx.x * 256 + threadIdx.x;
    if (i < n) fcw1b[i] = f2bf(fcw1[i]);
}

// ---------------- Kernel 3: fused BN-apply + conv1 (VALU) + conv2 (MFMA) + pool
__global__ __launch_bounds__(256, 2) void k_conv(const float* __restrict__ x,
    const float* __restrict__ w1, const float* __restrict__ b1,
    const u16* __restrict__ w2b, const float* __restrict__ b2,
    const float* __restrict__ stats, u16* __restrict__ pooled)
{
    __shared__ u16 h1[28800];          // [g=ch/8][30*30 py][ch%8] bf16
    __shared__ float feat[30][30];
    __shared__ unsigned char mk[784];
    const int t = threadIdx.x;
    const int b = blockIdx.x;
    const int lane = t & 63;
    const int wv = t >> 6;
    const int lg = lane >> 4;
    const int lr = lane & 15;

    bf16x8 wf[9][4];
    #pragma unroll
    for (int tap = 0; tap < 9; ++tap)
        #pragma unroll
        for (int nt = 0; nt < 4; ++nt)
            wf[tap][nt] = *(const bf16x8*)(w2b + tap * 2048 + (nt * 16 + lr) * 32 + lg * 8);
    float bias2[4];
    #pragma unroll
    for (int nt = 0; nt < 4; ++nt) bias2[nt] = b2[nt * 16 + lr];

    const float scale = stats[4], shift = stats[5];

    for (int i = t; i < 14400; i += 256) ((u32*)h1)[i] = 0u;
    for (int i = t; i < 900; i += 256) (&feat[0][0])[i] = 0.f;
    __syncthreads();

    const float* xb = x + (size_t)b * 784;
    for (int i = t; i < 784; i += 256) {
        float v = xb[i];
        bool m = (v != 0.f);
        mk[i] = m ? 1 : 0;
        int h = i / 28, w = i - h * 28;
        feat[h + 1][w + 1] = m ? fmaf(v, scale, shift) : 0.f;
    }
    __syncthreads();

    // conv1
    {
        const int cp = t & 15, pxg = t >> 4;
        float wk0[9], wk1[9];
        const float bs0 = b1[2 * cp], bs1 = b1[2 * cp + 1];
        #pragma unroll
        for (int j = 0; j < 9; ++j) {
            wk0[j] = w1[j * 32 + 2 * cp];
            wk1[j] = w1[j * 32 + 2 * cp + 1];
        }
        const int hslot = (cp >> 2) * 7200 + (cp & 3) * 2;
        for (int px = pxg; px < 784; px += 16) {
            if (!mk[px]) continue;
            int h = px / 28, w = px - h * 28;
            float a0 = bs0, a1 = bs1;
            #pragma unroll
            for (int kh = 0; kh < 3; ++kh)
                #pragma unroll
                for (int kw = 0; kw < 3; ++kw) {
                    float f = feat[h + kh][w + kw];
                    a0 = fmaf(f, wk0[kh * 3 + kw], a0);
                    a1 = fmaf(f, wk1[kh * 3 + kw], a1);
                }
            u32 pk = (u32)f2bf(fmaxf(a0, 0.f)) | ((u32)f2bf(fmaxf(a1, 0.f)) << 16);
            *(u32*)&h1[hslot + ((h + 1) * 30 + (w + 1)) * 8] = pk;
        }
    }
    __syncthreads();

    // conv2 (MFMA) + bias + mask + ReLU + pool
    const int win = lr >> 2, dyl = (lr >> 1) & 1, dxl = lr & 1;
    const f32x4 zero4 = {0.f, 0.f, 0.f, 0.f};
    for (int mt = wv; mt < 56; mt += 4) {
        const int r = mt >> 2, cg = mt & 3;
        const int ih = 2 * r + dyl;
        int iw = 2 * (cg * 4 + win) + dxl;
        if (iw > 27) iw = 27;
        const char* abase = (const char*)h1 + lg * 14400 + (ih * 30 + iw) * 16;

        f32x4 acc[4];
        #pragma unroll
        for (int nt = 0; nt < 4; ++nt) acc[nt] = zero4;

        #pragma unroll
        for (int tap = 0; tap < 9; ++tap) {
            const int kh = tap / 3, kw = tap - kh * 3;
            bf16x8 af = *(const bf16x8*)(abase + (kh * 30 + kw) * 16);
            #pragma unroll
            for (int nt = 0; nt < 4; ++nt)
                acc[nt] = __builtin_amdgcn_mfma_f32_16x16x32_bf16(af, wf[tap][nt], acc[nt], 0, 0, 0);
        }

        const int pc = cg * 4 + lg;
        if (pc < 14) {
            const int m00 = mk[(2 * r) * 28 + 2 * pc];
            const int m01 = mk[(2 * r) * 28 + 2 * pc + 1];
            const int m10 = mk[(2 * r + 1) * 28 + 2 * pc];
            const int m11 = mk[(2 * r + 1) * 28 + 2 * pc + 1];
            #pragma unroll
            for (int nt = 0; nt < 4; ++nt) {
                float v0 = m00 ? fmaxf(acc[nt][0] + bias2[nt], 0.f) : 0.f;
                float v1 = m01 ? fmaxf(acc[nt][1] + bias2[nt], 0.f) : 0.f;
                float v2 = m10 ? fmaxf(acc[nt][2] + bias2[nt], 0.f) : 0.f;
                float v3 = m11 ? fmaxf(acc[nt][3] + bias2[nt], 0.f) : 0.f;
                float best = fmaxf(fmaxf(v0, v1), fmaxf(v2, v3));
                pooled[(size_t)b * 12544 + (nt * 16 + lr) * 196 + r * 14 + pc] = f2bf(best);
            }
        }
    }
}

// ---------------- Kernel 4: FC1 MFMA GEMM. C[m][n] += sum_k pooled[m][k]*fcw1b[n][k]
// BM=64, BN=128, BK=64, splitK=14 (K-chunk 896 = 14 steps). fc1 layout [m][128].
__global__ __launch_bounds__(256, 4) void k_fc1(const u16* __restrict__ pooled,
    const u16* __restrict__ fcw1b, float* __restrict__ fc1, int M)
{
    __shared__ u16 Asm[8 * 64 * 8];    // [kq][row][8]  8KB
    __shared__ u16 Bsm[8 * 128 * 8];   // [kq][col][8] 16KB
    const int t = threadIdx.x;
    const int m0 = blockIdx.x * 64;
    const int kbase = blockIdx.y * 896;
    const int lane = t & 63;
    const int wv = t >> 6;
    const int lg = lane >> 4, lr = lane & 15;
    const int wm = wv & 1, wn = wv >> 1;

    // staging sources (element offsets; add k each step)
    const int ia0 = t, ia1 = t + 256;
    const u16* as0 = pooled + (size_t)(m0 + (ia0 & 63)) * 12544 + (ia0 >> 6) * 8 + kbase;
    const u16* as1 = pooled + (size_t)(m0 + (ia1 & 63)) * 12544 + (ia1 >> 6) * 8 + kbase;
    const u16* bs0 = fcw1b + (size_t)(t & 127) * 12544 + ((t >> 7) + 0) * 8 + kbase;
    const u16* bs1 = fcw1b + (size_t)(t & 127) * 12544 + ((t >> 7) + 2) * 8 + kbase;
    const u16* bs2 = fcw1b + (size_t)(t & 127) * 12544 + ((t >> 7) + 4) * 8 + kbase;
    const u16* bs3 = fcw1b + (size_t)(t & 127) * 12544 + ((t >> 7) + 6) * 8 + kbase;
    u16* ad0 = &Asm[(size_t)ia0 * 8];
    u16* ad1 = &Asm[(size_t)ia1 * 8];
    u16* bd0 = &Bsm[(size_t)(t + 0) * 8];
    u16* bd1 = &Bsm[(size_t)(t + 256) * 8];
    u16* bd2 = &Bsm[(size_t)(t + 512) * 8];
    u16* bd3 = &Bsm[(size_t)(t + 768) * 8];

    f32x4 acc[2][4];
    #pragma unroll
    for (int mi = 0; mi < 2; ++mi)
        #pragma unroll
        for (int ni = 0; ni < 4; ++ni) acc[mi][ni] = (f32x4){0.f, 0.f, 0.f, 0.f};

    for (int s = 0; s < 14; ++s) {
        const int kk = s * 64;
        __syncthreads();
        gload16(as0 + kk, ad0);
        gload16(as1 + kk, ad1);
        gload16(bs0 + kk, bd0);
        gload16(bs1 + kk, bd1);
        gload16(bs2 + kk, bd2);
        gload16(bs3 + kk, bd3);
        asm volatile("s_waitcnt vmcnt(0)" ::: "memory");
        __syncthreads();
        #pragma unroll
        for (int ks = 0; ks < 2; ++ks) {
            bf16x8 a[2], bfr[4];
            #pragma unroll
            for (int mi = 0; mi < 2; ++mi)
                a[mi] = *(const bf16x8*)&Asm[(((ks * 4 + lg) * 64) + wm * 32 + mi * 16 + lr) * 8];
            #pragma unroll
            for (int ni = 0; ni < 4; ++ni)
                bfr[ni] = *(const bf16x8*)&Bsm[(((ks * 4 + lg) * 128) + wn * 64 + ni * 16 + lr) * 8];
            #pragma unroll
            for (int mi = 0; mi < 2; ++mi)
                #pragma unroll
                for (int ni = 0; ni < 4; ++ni)
                    acc[mi][ni] = __builtin_amdgcn_mfma_f32_16x16x32_bf16(a[mi], bfr[ni], acc[mi][ni], 0, 0, 0);
        }
    }

    #pragma unroll
    for (int mi = 0; mi < 2; ++mi)
        #pragma unroll
        for (int ni = 0; ni < 4; ++ni)
            #pragma unroll
            for (int q = 0; q < 4; ++q) {
                int m = m0 + wm * 32 + mi * 16 + lg * 4 + q;
                int n = wn * 64 + ni * 16 + lr;
                atomicAdd(&fc1[(size_t)m * 128 + n], acc[mi][ni][q]);
            }
}

// ---------------- Kernel 5: bias+ReLU + FC2 + log_softmax (64 m/block, 4 k-slices)
__global__ __launch_bounds__(256) void k_fc2(const float* __restrict__ fc1,
    const float* __restrict__ fcb1, const float* __restrict__ fcw2,
    const float* __restrict__ fcb2, float* __restrict__ out, int M)
{
    __shared__ float red[4][64][10];
    const int t = threadIdx.x;
    const int ml = t & 63, kq = t >> 6;
    const int m = blockIdx.x * 64 + ml;
    float acc[10];
    #pragma unroll
    for (int c = 0; c < 10; ++c) acc[c] = 0.f;
    const float* fp = fc1 + (size_t)m * 128 + kq * 32;
    #pragma unroll 2
    for (int j = 0; j < 32; j += 4) {
        float4 v4 = *(const float4*)(fp + j);
        float vv[4] = {v4.x, v4.y, v4.z, v4.w};
        #pragma unroll
        for (int u = 0; u < 4; ++u) {
            int k = kq * 32 + j + u;
            float v = fmaxf(vv[u] + fcb1[k], 0.f);
            #pragma unroll
            for (int c = 0; c < 10; ++c) acc[c] = fmaf(v, fcw2[c * 128 + k], acc[c]);
        }
    }
    #pragma unroll
    for (int c = 0; c < 10; ++c) red[kq][ml][c] = acc[c];
    __syncthreads();
    if (kq == 0) {
        float lgt[10];
        #pragma unroll
        for (int c = 0; c < 10; ++c)
            lgt[c] = red[0][ml][c] + red[1][ml][c] + red[2][ml][c] + red[3][ml][c] + fcb2[c];
        float mx = lgt[0];
        #pragma unroll
        for (int c = 1; c < 10; ++c) mx = fmaxf(mx, lgt[c]);
        float se = 0.f;
        #pragma unroll
        for (int c = 0; c < 10; ++c) se += expf(lgt[c] - mx);
        float lse = mx + logf(se);
        #pragma unroll
        for (int c = 0; c < 10; ++c) out[(size_t)m * 10 + c] = lgt[c] - lse;
    }
}

extern "C" void kernel_launch(void* const* d_in, const int* in_sizes, int n_in,
                              void* d_out, int out_size, void* d_ws, size_t ws_size,
                              hipStream_t stream) {
    const float* x     = (const float*)d_in[0];
    const float* gamma = (const float*)d_in[1];
    const float* beta  = (const float*)d_in[2];
    const float* w1    = (const float*)d_in[3];
    const float* b1    = (const float*)d_in[4];
    const float* w2    = (const float*)d_in[5];
    const float* b2    = (const float*)d_in[6];
    const float* fcw1  = (const float*)d_in[7];
    const float* fcb1  = (const float*)d_in[8];
    const float* fcw2  = (const float*)d_in[9];
    const float* fcb2  = (const float*)d_in[10];
    float* out = (float*)d_out;

    const int B = in_sizes[0] / 784;  // 4096

    // ws layout: stats(256) | fc1 [M][128] f32 (2MB, aliased by w2b pre-conv)
    //            | pooled [M][12544] bf16 | fcw1b [128][12544] bf16
    float* stats  = (float*)d_ws;
    u16*   w2b    = (u16*)((char*)d_ws + 256);
    float* fc1    = (float*)((char*)d_ws + 256);
    u16*   pooled = (u16*)((char*)d_ws + 256 + (size_t)B * 128 * 4);
    u16*   fcw1b  = (u16*)((char*)d_ws + 256 + (size_t)B * 128 * 4 + (size_t)B * 12544 * 2);

    hipMemsetAsync(stats, 0, 32, stream);
    k_stats<<<1024, 256, 0, stream>>>(x, B * 784, stats);
    k_finalize<<<1, 1, 0, stream>>>(gamma, beta, stats);
    k_prep<<<72, 256, 0, stream>>>(w2, w2b);
    k_prepw<<<(128 * 12544 + 255) / 256, 256, 0, stream>>>(fcw1, fcw1b, 128 * 12544);
    k_conv<<<B, 256, 0, stream>>>(x, w1, b1, w2b, b2, stats, pooled);
    hipMemsetAsync(fc1, 0, (size_t)B * 128 * 4, stream);
    k_fc1<<<dim3(B / 64, 14), 256, 0, stream>>>(pooled, fcw1b, fc1, B);
    k_fc2<<<B / 64, 256, 0, stream>>>(fc1, fcb1, fcw2, fcb2, out, B);
}

// Round 5
// 390.430 us; speedup vs baseline: 529.3190x; 1.0237x over previous
//
#include <hip/hip_runtime.h>
#include <stdint.h>

typedef unsigned short u16;
typedef unsigned int u32;
typedef __attribute__((ext_vector_type(8))) short bf16x8;
typedef __attribute__((ext_vector_type(4))) float f32x4;

__device__ __forceinline__ u16 f2bf(float f) {
    u32 u = __float_as_uint(f);
    u32 r = (u + 0x7fffu + ((u >> 16) & 1u)) >> 16;
    return (u16)r;
}

__device__ __forceinline__ void gload16(const u16* src, u16* dst) {
    __builtin_amdgcn_global_load_lds(
        (const __attribute__((address_space(1))) u32*)src,
        (__attribute__((address_space(3))) u32*)dst, 16, 0, 0);
}

// ---------------- Kernel 1: BN statistics
__global__ __launch_bounds__(256) void k_stats(const float* __restrict__ x, int n,
                                               float* __restrict__ stats) {
    int t = blockIdx.x * 256 + threadIdx.x;
    int stride = gridDim.x * 256;
    float c = 0.f, s = 0.f, ss = 0.f;
    for (int i = t; i < n; i += stride) {
        float v = x[i];
        if (v != 0.f) { c += 1.f; s += v; ss = fmaf(v, v, ss); }
    }
    for (int off = 32; off > 0; off >>= 1) {
        c  += __shfl_down(c, off);
        s  += __shfl_down(s, off);
        ss += __shfl_down(ss, off);
    }
    __shared__ float red[3][4];
    int lane = threadIdx.x & 63, wv = threadIdx.x >> 6;
    if (lane == 0) { red[0][wv] = c; red[1][wv] = s; red[2][wv] = ss; }
    __syncthreads();
    if (threadIdx.x == 0) {
        atomicAdd(&stats[0], red[0][0] + red[0][1] + red[0][2] + red[0][3]);
        atomicAdd(&stats[1], red[1][0] + red[1][1] + red[1][2] + red[1][3]);
        atomicAdd(&stats[2], red[2][0] + red[2][1] + red[2][2] + red[2][3]);
    }
}

// ---------------- Kernel 2: finalize BN affine
__global__ void k_finalize(const float* __restrict__ g, const float* __restrict__ b,
                           float* __restrict__ stats) {
    float n = stats[0]; if (n < 1.f) n = 1.f;
    float mean = stats[1] / n;
    float var = stats[2] / n - mean * mean;
    if (var < 0.f) var = 0.f;
    float scale = g[0] * rsqrtf(var + 1e-5f);
    stats[4] = scale;
    stats[5] = b[0] - mean * scale;
}

// ---------------- Kernel 2b: merged weight prep (w2 -> w2b bf16, fcw1 -> fcw1b bf16)
__global__ __launch_bounds__(256) void k_prepall(const float* __restrict__ w2,
    const float* __restrict__ fcw1, u16* __restrict__ w2b, u16* __restrict__ fcw1b, int n)
{
    int i = blockIdx.x * 256 + threadIdx.x;
    if (i < 9 * 64 * 32) {
        int tap = i >> 11, rem = i & 2047, co = rem >> 5, ci = rem & 31;
        w2b[i] = f2bf(w2[tap * 2048 + ci * 64 + co]);
    }
    if (i < n) fcw1b[i] = f2bf(fcw1[i]);
}

// ---------------- Kernel 3: fused BN-apply + conv1 (VALU, 4ch/thr) + conv2 (MFMA) + pool
// 512 threads (8 waves), one image per block, 2 blocks/CU target (16 waves/CU).
// conv2 waves: wn2 = wv&1 (n-half: 2 co-tiles), wq = wv>>1 (m-quarter: cg=wq, r=0..13).
__global__ __launch_bounds__(512, 4) void k_conv(const float* __restrict__ x,
    const float* __restrict__ w1, const float* __restrict__ b1,
    const u16* __restrict__ w2b, const float* __restrict__ b2,
    const float* __restrict__ stats, u16* __restrict__ pooled)
{
    __shared__ u16 h1[28800];          // [g=ch/8][30*30 py][ch%8] bf16
    __shared__ float feat[30][30];
    __shared__ unsigned char mk[784];
    __shared__ unsigned char pm[196];  // packed 2x2 pool-window masks
    const int t = threadIdx.x;
    const int b = blockIdx.x;
    const int lane = t & 63;
    const int wv = t >> 6;             // wave 0..7
    const int lg = lane >> 4;
    const int lr = lane & 15;
    const int wn2 = wv & 1;            // n-half
    const int wq = wv >> 1;            // m-quarter (= cg)

    // conv2 B-fragments: 2 co-tiles for this wave's n-half
    bf16x8 wf[9][2];
    #pragma unroll
    for (int tap = 0; tap < 9; ++tap)
        #pragma unroll
        for (int j = 0; j < 2; ++j)
            wf[tap][j] = *(const bf16x8*)(w2b + tap * 2048 + ((wn2 * 2 + j) * 16 + lr) * 32 + lg * 8);
    float bias2[2];
    #pragma unroll
    for (int j = 0; j < 2; ++j) bias2[j] = b2[(wn2 * 2 + j) * 16 + lr];

    const float scale = stats[4], shift = stats[5];

    for (int i = t; i < 14400; i += 512) ((u32*)h1)[i] = 0u;
    for (int i = t; i < 900; i += 512) (&feat[0][0])[i] = 0.f;
    __syncthreads();

    const float* xb = x + (size_t)b * 784;
    for (int i = t; i < 784; i += 512) {
        float v = xb[i];
        bool m = (v != 0.f);
        mk[i] = m ? 1 : 0;
        int h = i / 28, w = i - h * 28;
        feat[h + 1][w + 1] = m ? fmaf(v, scale, shift) : 0.f;
    }
    __syncthreads();

    // pool-window mask pack (reads mk, written before the conv1->conv2 barrier)
    if (t < 196) {
        int rr = t / 14, cc = t - rr * 14;
        int base = rr * 56 + cc * 2;
        pm[t] = (unsigned char)(mk[base] | (mk[base + 1] << 1)
              | (mk[base + 28] << 2) | (mk[base + 29] << 3));
    }

    // conv1: 4 output channels per thread, 64 pixel groups
    {
        const int cp = t & 7, pxg = t >> 3;
        float wk[9][4];
        float bs[4];
        #pragma unroll
        for (int c = 0; c < 4; ++c) bs[c] = b1[cp * 4 + c];
        #pragma unroll
        for (int j = 0; j < 9; ++j)
            #pragma unroll
            for (int c = 0; c < 4; ++c) wk[j][c] = w1[j * 32 + cp * 4 + c];
        u16* hb = h1 + (cp >> 1) * 7200 + (cp & 1) * 4;   // u16 units
        for (int px = pxg; px < 784; px += 64) {
            if (!mk[px]) continue;
            int h = px / 28, w = px - h * 28;
            float a0 = bs[0], a1 = bs[1], a2 = bs[2], a3 = bs[3];
            #pragma unroll
            for (int kh = 0; kh < 3; ++kh)
                #pragma unroll
                for (int kw = 0; kw < 3; ++kw) {
                    float f = feat[h + kh][w + kw];
                    a0 = fmaf(f, wk[kh * 3 + kw][0], a0);
                    a1 = fmaf(f, wk[kh * 3 + kw][1], a1);
                    a2 = fmaf(f, wk[kh * 3 + kw][2], a2);
                    a3 = fmaf(f, wk[kh * 3 + kw][3], a3);
                }
            u32 lo = (u32)f2bf(fmaxf(a0, 0.f)) | ((u32)f2bf(fmaxf(a1, 0.f)) << 16);
            u32 hi = (u32)f2bf(fmaxf(a2, 0.f)) | ((u32)f2bf(fmaxf(a3, 0.f)) << 16);
            *(uint2*)&hb[((h + 1) * 30 + (w + 1)) * 8] = make_uint2(lo, hi);
        }
    }
    __syncthreads();

    // conv2 (MFMA) + mask + ReLU + pool.  Per wave: 14 m-tiles (r=0..13), cg=wq fixed.
    const int win = lr >> 2, dyl = (lr >> 1) & 1, dxl = lr & 1;
    int iw = 2 * (wq * 4 + win) + dxl;
    if (iw > 27) iw = 27;               // clamp padded lanes (rows discarded)
    const int pc = wq * 4 + lg;
    u16* poolb = pooled + (size_t)b * 12544;
    for (int r = 0; r < 14; ++r) {
        const int ih = 2 * r + dyl;
        const char* abase = (const char*)h1 + lg * 14400 + (ih * 30 + iw) * 16;

        f32x4 acc0 = {bias2[0], bias2[0], bias2[0], bias2[0]};
        f32x4 acc1 = {bias2[1], bias2[1], bias2[1], bias2[1]};
        #pragma unroll
        for (int tap = 0; tap < 9; ++tap) {
            const int kh = tap / 3, kw = tap - kh * 3;
            bf16x8 af = *(const bf16x8*)(abase + (kh * 30 + kw) * 16);
            acc0 = __builtin_amdgcn_mfma_f32_16x16x32_bf16(af, wf[tap][0], acc0, 0, 0, 0);
            acc1 = __builtin_amdgcn_mfma_f32_16x16x32_bf16(af, wf[tap][1], acc1, 0, 0, 0);
        }

        if (pc < 14) {
            int pmv = pm[r * 14 + pc];
            float mf0 = (pmv & 1) ? 1.f : 0.f;
            float mf1 = (pmv & 2) ? 1.f : 0.f;
            float mf2 = (pmv & 4) ? 1.f : 0.f;
            float mf3 = (pmv & 8) ? 1.f : 0.f;
            {
                float v0 = fmaxf(acc0[0], 0.f) * mf0;
                float v1 = fmaxf(acc0[1], 0.f) * mf1;
                float v2 = fmaxf(acc0[2], 0.f) * mf2;
                float v3 = fmaxf(acc0[3], 0.f) * mf3;
                float best = fmaxf(fmaxf(v0, v1), fmaxf(v2, v3));
                poolb[((wn2 * 2 + 0) * 16 + lr) * 196 + r * 14 + pc] = f2bf(best);
            }
            {
                float v0 = fmaxf(acc1[0], 0.f) * mf0;
                float v1 = fmaxf(acc1[1], 0.f) * mf1;
                float v2 = fmaxf(acc1[2], 0.f) * mf2;
                float v3 = fmaxf(acc1[3], 0.f) * mf3;
                float best = fmaxf(fmaxf(v0, v1), fmaxf(v2, v3));
                poolb[((wn2 * 2 + 1) * 16 + lr) * 196 + r * 14 + pc] = f2bf(best);
            }
        }
    }
}

// ---------------- Kernel 4: FC1 MFMA GEMM. C[m][n] += sum_k pooled[m][k]*fcw1b[n][k]
// BM=64, BN=128, BK=64, splitK=14. fc1 layout [m][128].
__global__ __launch_bounds__(256, 4) void k_fc1(const u16* __restrict__ pooled,
    const u16* __restrict__ fcw1b, float* __restrict__ fc1, int M)
{
    __shared__ u16 Asm[8 * 64 * 8];    // [kq][row][8]  8KB
    __shared__ u16 Bsm[8 * 128 * 8];   // [kq][col][8] 16KB
    const int t = threadIdx.x;
    const int m0 = blockIdx.x * 64;
    const int kbase = blockIdx.y * 896;
    const int lane = t & 63;
    const int wv = t >> 6;
    const int lg = lane >> 4, lr = lane & 15;
    const int wm = wv & 1, wn = wv >> 1;

    const int ia0 = t, ia1 = t + 256;
    const u16* as0 = pooled + (size_t)(m0 + (ia0 & 63)) * 12544 + (ia0 >> 6) * 8 + kbase;
    const u16* as1 = pooled + (size_t)(m0 + (ia1 & 63)) * 12544 + (ia1 >> 6) * 8 + kbase;
    const u16* bs0 = fcw1b + (size_t)(t & 127) * 12544 + ((t >> 7) + 0) * 8 + kbase;
    const u16* bs1 = fcw1b + (size_t)(t & 127) * 12544 + ((t >> 7) + 2) * 8 + kbase;
    const u16* bs2 = fcw1b + (size_t)(t & 127) * 12544 + ((t >> 7) + 4) * 8 + kbase;
    const u16* bs3 = fcw1b + (size_t)(t & 127) * 12544 + ((t >> 7) + 6) * 8 + kbase;
    u16* ad0 = &Asm[(size_t)ia0 * 8];
    u16* ad1 = &Asm[(size_t)ia1 * 8];
    u16* bd0 = &Bsm[(size_t)(t + 0) * 8];
    u16* bd1 = &Bsm[(size_t)(t + 256) * 8];
    u16* bd2 = &Bsm[(size_t)(t + 512) * 8];
    u16* bd3 = &Bsm[(size_t)(t + 768) * 8];

    f32x4 acc[2][4];
    #pragma unroll
    for (int mi = 0; mi < 2; ++mi)
        #pragma unroll
        for (int ni = 0; ni < 4; ++ni) acc[mi][ni] = (f32x4){0.f, 0.f, 0.f, 0.f};

    for (int s = 0; s < 14; ++s) {
        const int kk = s * 64;
        __syncthreads();
        gload16(as0 + kk, ad0);
        gload16(as1 + kk, ad1);
        gload16(bs0 + kk, bd0);
        gload16(bs1 + kk, bd1);
        gload16(bs2 + kk, bd2);
        gload16(bs3 + kk, bd3);
        asm volatile("s_waitcnt vmcnt(0)" ::: "memory");
        __syncthreads();
        #pragma unroll
        for (int ks = 0; ks < 2; ++ks) {
            bf16x8 a[2], bfr[4];
            #pragma unroll
            for (int mi = 0; mi < 2; ++mi)
                a[mi] = *(const bf16x8*)&Asm[(((ks * 4 + lg) * 64) + wm * 32 + mi * 16 + lr) * 8];
            #pragma unroll
            for (int ni = 0; ni < 4; ++ni)
                bfr[ni] = *(const bf16x8*)&Bsm[(((ks * 4 + lg) * 128) + wn * 64 + ni * 16 + lr) * 8];
            #pragma unroll
            for (int mi = 0; mi < 2; ++mi)
                #pragma unroll
                for (int ni = 0; ni < 4; ++ni)
                    acc[mi][ni] = __builtin_amdgcn_mfma_f32_16x16x32_bf16(a[mi], bfr[ni], acc[mi][ni], 0, 0, 0);
        }
    }

    #pragma unroll
    for (int mi = 0; mi < 2; ++mi)
        #pragma unroll
        for (int ni = 0; ni < 4; ++ni)
            #pragma unroll
            for (int q = 0; q < 4; ++q) {
                int m = m0 + wm * 32 + mi * 16 + lg * 4 + q;
                int n = wn * 64 + ni * 16 + lr;
                atomicAdd(&fc1[(size_t)m * 128 + n], acc[mi][ni][q]);
            }
}

// ---------------- Kernel 5: bias+ReLU + FC2 + log_softmax (64 m/block, 4 k-slices)
__global__ __launch_bounds__(256) void k_fc2(const float* __restrict__ fc1,
    const float* __restrict__ fcb1, const float* __restrict__ fcw2,
    const float* __restrict__ fcb2, float* __restrict__ out, int M)
{
    __shared__ float red[4][64][10];
    const int t = threadIdx.x;
    const int ml = t & 63, kq = t >> 6;
    const int m = blockIdx.x * 64 + ml;
    float acc[10];
    #pragma unroll
    for (int c = 0; c < 10; ++c) acc[c] = 0.f;
    const float* fp = fc1 + (size_t)m * 128 + kq * 32;
    #pragma unroll 2
    for (int j = 0; j < 32; j += 4) {
        float4 v4 = *(const float4*)(fp + j);
        float vv[4] = {v4.x, v4.y, v4.z, v4.w};
        #pragma unroll
        for (int u = 0; u < 4; ++u) {
            int k = kq * 32 + j + u;
            float v = fmaxf(vv[u] + fcb1[k], 0.f);
            #pragma unroll
            for (int c = 0; c < 10; ++c) acc[c] = fmaf(v, fcw2[c * 128 + k], acc[c]);
        }
    }
    #pragma unroll
    for (int c = 0; c < 10; ++c) red[kq][ml][c] = acc[c];
    __syncthreads();
    if (kq == 0) {
        float lgt[10];
        #pragma unroll
        for (int c = 0; c < 10; ++c)
            lgt[c] = red[0][ml][c] + red[1][ml][c] + red[2][ml][c] + red[3][ml][c] + fcb2[c];
        float mx = lgt[0];
        #pragma unroll
        for (int c = 1; c < 10; ++c) mx = fmaxf(mx, lgt[c]);
        float se = 0.f;
        #pragma unroll
        for (int c = 0; c < 10; ++c) se += expf(lgt[c] - mx);
        float lse = mx + logf(se);
        #pragma unroll
        for (int c = 0; c < 10; ++c) out[(size_t)m * 10 + c] = lgt[c] - lse;
    }
}

extern "C" void kernel_launch(void* const* d_in, const int* in_sizes, int n_in,
                              void* d_out, int out_size, void* d_ws, size_t ws_size,
                              hipStream_t stream) {
    const float* x     = (const float*)d_in[0];
    const float* gamma = (const float*)d_in[1];
    const float* beta  = (const float*)d_in[2];
    const float* w1    = (const float*)d_in[3];
    const float* b1    = (const float*)d_in[4];
    const float* w2    = (const float*)d_in[5];
    const float* b2    = (const float*)d_in[6];
    const float* fcw1  = (const float*)d_in[7];
    const float* fcb1  = (const float*)d_in[8];
    const float* fcw2  = (const float*)d_in[9];
    const float* fcb2  = (const float*)d_in[10];
    float* out = (float*)d_out;

    const int B = in_sizes[0] / 784;  // 4096

    // ws: stats(256) | fc1 [M][128] f32 (aliased by w2b pre-conv) | pooled | fcw1b
    float* stats  = (float*)d_ws;
    u16*   w2b    = (u16*)((char*)d_ws + 256);
    float* fc1    = (float*)((char*)d_ws + 256);
    u16*   pooled = (u16*)((char*)d_ws + 256 + (size_t)B * 128 * 4);
    u16*   fcw1b  = (u16*)((char*)d_ws + 256 + (size_t)B * 128 * 4 + (size_t)B * 12544 * 2);

    hipMemsetAsync(stats, 0, 32, stream);
    k_stats<<<1024, 256, 0, stream>>>(x, B * 784, stats);
    k_finalize<<<1, 1, 0, stream>>>(gamma, beta, stats);
    k_prepall<<<(128 * 12544 + 255) / 256, 256, 0, stream>>>(w2, fcw1, w2b, fcw1b, 128 * 12544);
    k_conv<<<B, 512, 0, stream>>>(x, w1, b1, w2b, b2, stats, pooled);
    hipMemsetAsync(fc1, 0, (size_t)B * 128 * 4, stream);
    k_fc1<<<dim3(B / 64, 14), 256, 0, stream>>>(pooled, fcw1b, fc1, B);
    k_fc2<<<B / 64, 256, 0, stream>>>(fc1, fcb1, fcw2, fcb2, out, B);
}

// Round 6
// 349.972 us; speedup vs baseline: 590.5112x; 1.1156x over previous
//
#include <hip/hip_runtime.h>
#include <stdint.h>

typedef unsigned short u16;
typedef unsigned int u32;
typedef __attribute__((ext_vector_type(8))) short bf16x8;
typedef __attribute__((ext_vector_type(4))) float f32x4;

__device__ __forceinline__ u16 f2bf(float f) {
    u32 u = __float_as_uint(f);
    u32 r = (u + 0x7fffu + ((u >> 16) & 1u)) >> 16;
    return (u16)r;
}

__device__ __forceinline__ void gload16(const u16* src, u16* dst) {
    __builtin_amdgcn_global_load_lds(
        (const __attribute__((address_space(1))) u32*)src,
        (__attribute__((address_space(3))) u32*)dst, 16, 0, 0);
}

// ---------------- Kernel 1: BN statistics
__global__ __launch_bounds__(256) void k_stats(const float* __restrict__ x, int n,
                                               float* __restrict__ stats) {
    int t = blockIdx.x * 256 + threadIdx.x;
    int stride = gridDim.x * 256;
    float c = 0.f, s = 0.f, ss = 0.f;
    for (int i = t; i < n; i += stride) {
        float v = x[i];
        if (v != 0.f) { c += 1.f; s += v; ss = fmaf(v, v, ss); }
    }
    for (int off = 32; off > 0; off >>= 1) {
        c  += __shfl_down(c, off);
        s  += __shfl_down(s, off);
        ss += __shfl_down(ss, off);
    }
    __shared__ float red[3][4];
    int lane = threadIdx.x & 63, wv = threadIdx.x >> 6;
    if (lane == 0) { red[0][wv] = c; red[1][wv] = s; red[2][wv] = ss; }
    __syncthreads();
    if (threadIdx.x == 0) {
        atomicAdd(&stats[0], red[0][0] + red[0][1] + red[0][2] + red[0][3]);
        atomicAdd(&stats[1], red[1][0] + red[1][1] + red[1][2] + red[1][3]);
        atomicAdd(&stats[2], red[2][0] + red[2][1] + red[2][2] + red[2][3]);
    }
}

// ---------------- Kernel 2: finalize BN affine
__global__ void k_finalize(const float* __restrict__ g, const float* __restrict__ b,
                           float* __restrict__ stats) {
    float n = stats[0]; if (n < 1.f) n = 1.f;
    float mean = stats[1] / n;
    float var = stats[2] / n - mean * mean;
    if (var < 0.f) var = 0.f;
    float scale = g[0] * rsqrtf(var + 1e-5f);
    stats[4] = scale;
    stats[5] = b[0] - mean * scale;
}

// ---------------- Kernel 2b: merged weight prep (w2 -> w2b bf16, fcw1 -> fcw1b bf16)
__global__ __launch_bounds__(256) void k_prepall(const float* __restrict__ w2,
    const float* __restrict__ fcw1, u16* __restrict__ w2b, u16* __restrict__ fcw1b, int n)
{
    int i = blockIdx.x * 256 + threadIdx.x;
    if (i < 9 * 64 * 32) {
        int tap = i >> 11, rem = i & 2047, co = rem >> 5, ci = rem & 31;
        w2b[i] = f2bf(w2[tap * 2048 + ci * 64 + co]);
    }
    if (i < n) fcw1b[i] = f2bf(fcw1[i]);
}

// ---------------- Kernel 3: fused BN-apply + conv1 (VALU, 8ch/thr) + conv2 (MFMA) + pool
// 256 threads (4 waves), 1 image/block, 2 blocks/CU.
// h1: 4 groups (8ch) x 904 slots x 8ch bf16, group stride 14464 B.
// conv2: m-tile = 16 consecutive pixels of one row (lane lr = pixel col) -> contiguous
// conflict-free ds_read_b128. Each wave: full n (wf[9][4]), jobs = (r, cb): row-pair
// 2r,2r+1 at col-half cb; 12 unique A-frags feed 72 MFMAs. Pool fully in-lane.
__global__ __launch_bounds__(256, 2) void k_conv(const float* __restrict__ x,
    const float* __restrict__ w1, const float* __restrict__ b1,
    const u16* __restrict__ w2b, const float* __restrict__ b2,
    const float* __restrict__ stats, u16* __restrict__ pooled)
{
    __shared__ u16 h1[28928];            // 57856 B (4 x 14464)
    __shared__ float feat[30][30];
    __shared__ unsigned char mk[784];
    __shared__ unsigned char pm[200];    // packed 2x2 pool-window masks
    const int t = threadIdx.x;
    const int b = blockIdx.x;
    const int lane = t & 63;
    const int wv = t >> 6;               // wave 0..3
    const int lg = lane >> 4;            // k-group (8 ch)
    const int lr = lane & 15;            // A row (pixel) / D col (co)

    const float scale = stats[4], shift = stats[5];

    for (int i = t; i < 14464; i += 256) ((u32*)h1)[i] = 0u;
    for (int i = t; i < 900; i += 256) (&feat[0][0])[i] = 0.f;
    __syncthreads();

    const float* xb = x + (size_t)b * 784;
    for (int i = t; i < 784; i += 256) {
        float v = xb[i];
        bool m = (v != 0.f);
        mk[i] = m ? 1 : 0;
        int h = i / 28, w = i - h * 28;
        feat[h + 1][w + 1] = m ? fmaf(v, scale, shift) : 0.f;
    }
    __syncthreads();

    if (t < 196) {
        int rr = t / 14, cc = t - rr * 14;
        int base = rr * 56 + cc * 2;
        pm[t] = (unsigned char)(mk[base] | (mk[base + 1] << 1)
              | (mk[base + 28] << 2) | (mk[base + 29] << 3));
    }

    // conv1: 8 output channels per thread; quarter-wave = 16 consecutive pixels
    {
        const int cp = (t >> 4) & 3;                 // channel octet = h1 group
        const int pxg = (t & 15) | ((t >> 6) << 4);  // 0..63
        float wk[9][8], bs[8];
        {
            float4 b0 = *(const float4*)(b1 + cp * 8);
            float4 b4 = *(const float4*)(b1 + cp * 8 + 4);
            bs[0]=b0.x; bs[1]=b0.y; bs[2]=b0.z; bs[3]=b0.w;
            bs[4]=b4.x; bs[5]=b4.y; bs[6]=b4.z; bs[7]=b4.w;
        }
        #pragma unroll
        for (int j = 0; j < 9; ++j) {
            float4 w0 = *(const float4*)(w1 + j * 32 + cp * 8);
            float4 w4 = *(const float4*)(w1 + j * 32 + cp * 8 + 4);
            wk[j][0]=w0.x; wk[j][1]=w0.y; wk[j][2]=w0.z; wk[j][3]=w0.w;
            wk[j][4]=w4.x; wk[j][5]=w4.y; wk[j][6]=w4.z; wk[j][7]=w4.w;
        }
        char* hb = (char*)h1 + cp * 14464;
        for (int px = pxg; px < 784; px += 64) {
            if (!mk[px]) continue;
            int h = px / 28, w = px - h * 28;
            float a[8];
            #pragma unroll
            for (int c = 0; c < 8; ++c) a[c] = bs[c];
            #pragma unroll
            for (int kh = 0; kh < 3; ++kh)
                #pragma unroll
                for (int kw = 0; kw < 3; ++kw) {
                    float f = feat[h + kh][w + kw];
                    #pragma unroll
                    for (int c = 0; c < 8; ++c) a[c] = fmaf(f, wk[kh * 3 + kw][c], a[c]);
                }
            u32 q0 = (u32)f2bf(fmaxf(a[0], 0.f)) | ((u32)f2bf(fmaxf(a[1], 0.f)) << 16);
            u32 q1 = (u32)f2bf(fmaxf(a[2], 0.f)) | ((u32)f2bf(fmaxf(a[3], 0.f)) << 16);
            u32 q2 = (u32)f2bf(fmaxf(a[4], 0.f)) | ((u32)f2bf(fmaxf(a[5], 0.f)) << 16);
            u32 q3 = (u32)f2bf(fmaxf(a[6], 0.f)) | ((u32)f2bf(fmaxf(a[7], 0.f)) << 16);
            *(uint4*)(hb + ((h + 1) * 30 + (w + 1)) * 16) = make_uint4(q0, q1, q2, q3);
        }
    }
    __syncthreads();

    // conv2 weights/bias into regs (global, L1/L2-hot; loaded after conv1 to cap VGPR)
    bf16x8 wf[9][4];
    #pragma unroll
    for (int tap = 0; tap < 9; ++tap)
        #pragma unroll
        for (int nt = 0; nt < 4; ++nt)
            wf[tap][nt] = *(const bf16x8*)(w2b + tap * 2048 + (nt * 16 + lr) * 32 + lg * 8);
    float bias2[4];
    #pragma unroll
    for (int nt = 0; nt < 4; ++nt) bias2[nt] = b2[nt * 16 + lr];

    // conv2 (MFMA) + mask + ReLU + pool
    const int cb = wv & 1;               // col half (px 0-15 / 16-31pad)
    const int r0 = wv >> 1;              // row-pair parity
    const char* gb = (const char*)h1 + lg * 14464 + (cb * 16 + lr) * 16;
    const bool store_ok = !(cb == 1 && lg == 3);   // px >= 28 discarded
    const int pc0 = cb * 8 + lg * 2;
    u16* poolb = pooled + (size_t)b * 12544;

    #pragma unroll 1
    for (int i = 0; i < 7; ++i) {
        const int r = r0 + 2 * i;        // 0..13
        const char* ab = gb + 960 * r;   // slot row 2r (input row 2r-1)
        bf16x8 a0[3], a1[3], a2[3], a3[3];
        #pragma unroll
        for (int kw = 0; kw < 3; ++kw) {
            a0[kw] = *(const bf16x8*)(ab + kw * 16);
            a1[kw] = *(const bf16x8*)(ab + 480 + kw * 16);
            a2[kw] = *(const bf16x8*)(ab + 960 + kw * 16);
        }
        f32x4 acc0[4], acc1[4];
        #pragma unroll
        for (int nt = 0; nt < 4; ++nt) {
            acc0[nt] = (f32x4){bias2[nt], bias2[nt], bias2[nt], bias2[nt]};
            acc1[nt] = acc0[nt];
        }
        #pragma unroll
        for (int nt = 0; nt < 4; ++nt)
            #pragma unroll
            for (int kw = 0; kw < 3; ++kw) {
                acc0[nt] = __builtin_amdgcn_mfma_f32_16x16x32_bf16(a0[kw], wf[kw][nt], acc0[nt], 0, 0, 0);
                acc0[nt] = __builtin_amdgcn_mfma_f32_16x16x32_bf16(a1[kw], wf[3 + kw][nt], acc0[nt], 0, 0, 0);
                acc0[nt] = __builtin_amdgcn_mfma_f32_16x16x32_bf16(a2[kw], wf[6 + kw][nt], acc0[nt], 0, 0, 0);
            }
        #pragma unroll
        for (int kw = 0; kw < 3; ++kw)
            a3[kw] = *(const bf16x8*)(ab + 1440 + kw * 16);
        #pragma unroll
        for (int nt = 0; nt < 4; ++nt)
            #pragma unroll
            for (int kw = 0; kw < 3; ++kw) {
                acc1[nt] = __builtin_amdgcn_mfma_f32_16x16x32_bf16(a1[kw], wf[kw][nt], acc1[nt], 0, 0, 0);
                acc1[nt] = __builtin_amdgcn_mfma_f32_16x16x32_bf16(a2[kw], wf[3 + kw][nt], acc1[nt], 0, 0, 0);
                acc1[nt] = __builtin_amdgcn_mfma_f32_16x16x32_bf16(a3[kw], wf[6 + kw][nt], acc1[nt], 0, 0, 0);
            }

        if (store_ok) {
            u32 pmw = *(const u16*)&pm[r * 14 + pc0];
            float m00 = (pmw & 1u)    ? 1.f : 0.f, m01 = (pmw & 2u)    ? 1.f : 0.f;
            float m10 = (pmw & 4u)    ? 1.f : 0.f, m11 = (pmw & 8u)    ? 1.f : 0.f;
            float n00 = (pmw & 256u)  ? 1.f : 0.f, n01 = (pmw & 512u)  ? 1.f : 0.f;
            float n10 = (pmw & 1024u) ? 1.f : 0.f, n11 = (pmw & 2048u) ? 1.f : 0.f;
            #pragma unroll
            for (int nt = 0; nt < 4; ++nt) {
                float p0 = fmaxf(fmaxf(fmaxf(acc0[nt][0], 0.f) * m00, fmaxf(acc0[nt][1], 0.f) * m01),
                                 fmaxf(fmaxf(acc1[nt][0], 0.f) * m10, fmaxf(acc1[nt][1], 0.f) * m11));
                float p1 = fmaxf(fmaxf(fmaxf(acc0[nt][2], 0.f) * n00, fmaxf(acc0[nt][3], 0.f) * n01),
                                 fmaxf(fmaxf(acc1[nt][2], 0.f) * n10, fmaxf(acc1[nt][3], 0.f) * n11));
                *(u32*)&poolb[(nt * 16 + lr) * 196 + r * 14 + pc0] =
                    (u32)f2bf(p0) | ((u32)f2bf(p1) << 16);
            }
        }
    }
}

// ---------------- Kernel 4: FC1 MFMA GEMM. C[m][n] += sum_k pooled[m][k]*fcw1b[n][k]
// BM=64, BN=128, BK=64, splitK=7 (K-chunk 1792 = 28 steps). fc1 layout [m][128].
__global__ __launch_bounds__(256, 4) void k_fc1(const u16* __restrict__ pooled,
    const u16* __restrict__ fcw1b, float* __restrict__ fc1, int M)
{
    __shared__ u16 Asm[8 * 64 * 8];    // [kq][row][8]  8KB
    __shared__ u16 Bsm[8 * 128 * 8];   // [kq][col][8] 16KB
    const int t = threadIdx.x;
    const int m0 = blockIdx.x * 64;
    const int kbase = blockIdx.y * 1792;
    const int lane = t & 63;
    const int wv = t >> 6;
    const int lg = lane >> 4, lr = lane & 15;
    const int wm = wv & 1, wn = wv >> 1;

    const int ia0 = t, ia1 = t + 256;
    const u16* as0 = pooled + (size_t)(m0 + (ia0 & 63)) * 12544 + (ia0 >> 6) * 8 + kbase;
    const u16* as1 = pooled + (size_t)(m0 + (ia1 & 63)) * 12544 + (ia1 >> 6) * 8 + kbase;
    const u16* bs0 = fcw1b + (size_t)(t & 127) * 12544 + ((t >> 7) + 0) * 8 + kbase;
    const u16* bs1 = fcw1b + (size_t)(t & 127) * 12544 + ((t >> 7) + 2) * 8 + kbase;
    const u16* bs2 = fcw1b + (size_t)(t & 127) * 12544 + ((t >> 7) + 4) * 8 + kbase;
    const u16* bs3 = fcw1b + (size_t)(t & 127) * 12544 + ((t >> 7) + 6) * 8 + kbase;
    u16* ad0 = &Asm[(size_t)ia0 * 8];
    u16* ad1 = &Asm[(size_t)ia1 * 8];
    u16* bd0 = &Bsm[(size_t)(t + 0) * 8];
    u16* bd1 = &Bsm[(size_t)(t + 256) * 8];
    u16* bd2 = &Bsm[(size_t)(t + 512) * 8];
    u16* bd3 = &Bsm[(size_t)(t + 768) * 8];

    f32x4 acc[2][4];
    #pragma unroll
    for (int mi = 0; mi < 2; ++mi)
        #pragma unroll
        for (int ni = 0; ni < 4; ++ni) acc[mi][ni] = (f32x4){0.f, 0.f, 0.f, 0.f};

    for (int s = 0; s < 28; ++s) {
        const int kk = s * 64;
        __syncthreads();
        gload16(as0 + kk, ad0);
        gload16(as1 + kk, ad1);
        gload16(bs0 + kk, bd0);
        gload16(bs1 + kk, bd1);
        gload16(bs2 + kk, bd2);
        gload16(bs3 + kk, bd3);
        asm volatile("s_waitcnt vmcnt(0)" ::: "memory");
        __syncthreads();
        #pragma unroll
        for (int ks = 0; ks < 2; ++ks) {
            bf16x8 a[2], bfr[4];
            #pragma unroll
            for (int mi = 0; mi < 2; ++mi)
                a[mi] = *(const bf16x8*)&Asm[(((ks * 4 + lg) * 64) + wm * 32 + mi * 16 + lr) * 8];
            #pragma unroll
            for (int ni = 0; ni < 4; ++ni)
                bfr[ni] = *(const bf16x8*)&Bsm[(((ks * 4 + lg) * 128) + wn * 64 + ni * 16 + lr) * 8];
            #pragma unroll
            for (int mi = 0; mi < 2; ++mi)
                #pragma unroll
                for (int ni = 0; ni < 4; ++ni)
                    acc[mi][ni] = __builtin_amdgcn_mfma_f32_16x16x32_bf16(a[mi], bfr[ni], acc[mi][ni], 0, 0, 0);
        }
    }

    #pragma unroll
    for (int mi = 0; mi < 2; ++mi)
        #pragma unroll
        for (int ni = 0; ni < 4; ++ni)
            #pragma unroll
            for (int q = 0; q < 4; ++q) {
                int m = m0 + wm * 32 + mi * 16 + lg * 4 + q;
                int n = wn * 64 + ni * 16 + lr;
                atomicAdd(&fc1[(size_t)m * 128 + n], acc[mi][ni][q]);
            }
}

// ---------------- Kernel 5: bias+ReLU + FC2 + log_softmax (32 m/block, 8 k-slices)
__global__ __launch_bounds__(256) void k_fc2(const float* __restrict__ fc1,
    const float* __restrict__ fcb1, const float* __restrict__ fcw2,
    const float* __restrict__ fcb2, float* __restrict__ out, int M)
{
    __shared__ float red[8][32][10];
    const int t = threadIdx.x;
    const int ml = t & 31, kq = t >> 5;
    const int m = blockIdx.x * 32 + ml;
    float acc[10];
    #pragma unroll
    for (int c = 0; c < 10; ++c) acc[c] = 0.f;
    const float* fp = fc1 + (size_t)m * 128 + kq * 16;
    #pragma unroll
    for (int j = 0; j < 16; j += 4) {
        float4 v4 = *(const float4*)(fp + j);
        float vv[4] = {v4.x, v4.y, v4.z, v4.w};
        #pragma unroll
        for (int u = 0; u < 4; ++u) {
            int k = kq * 16 + j + u;
            float v = fmaxf(vv[u] + fcb1[k], 0.f);
            #pragma unroll
            for (int c = 0; c < 10; ++c) acc[c] = fmaf(v, fcw2[c * 128 + k], acc[c]);
        }
    }
    #pragma unroll
    for (int c = 0; c < 10; ++c) red[kq][ml][c] = acc[c];
    __syncthreads();
    if (kq == 0) {
        float lgt[10];
        #pragma unroll
        for (int c = 0; c < 10; ++c) {
            float sv = 0.f;
            #pragma unroll
            for (int s = 0; s < 8; ++s) sv += red[s][ml][c];
            lgt[c] = sv + fcb2[c];
        }
        float mx = lgt[0];
        #pragma unroll
        for (int c = 1; c < 10; ++c) mx = fmaxf(mx, lgt[c]);
        float se = 0.f;
        #pragma unroll
        for (int c = 0; c < 10; ++c) se += expf(lgt[c] - mx);
        float lse = mx + logf(se);
        #pragma unroll
        for (int c = 0; c < 10; ++c) out[(size_t)m * 10 + c] = lgt[c] - lse;
    }
}

extern "C" void kernel_launch(void* const* d_in, const int* in_sizes, int n_in,
                              void* d_out, int out_size, void* d_ws, size_t ws_size,
                              hipStream_t stream) {
    const float* x     = (const float*)d_in[0];
    const float* gamma = (const float*)d_in[1];
    const float* beta  = (const float*)d_in[2];
    const float* w1    = (const float*)d_in[3];
    const float* b1    = (const float*)d_in[4];
    const float* w2    = (const float*)d_in[5];
    const float* b2    = (const float*)d_in[6];
    const float* fcw1  = (const float*)d_in[7];
    const float* fcb1  = (const float*)d_in[8];
    const float* fcw2  = (const float*)d_in[9];
    const float* fcb2  = (const float*)d_in[10];
    float* out = (float*)d_out;

    const int B = in_sizes[0] / 784;  // 4096

    // ws: stats(256) | fc1 [M][128] f32 (aliased by w2b pre-conv) | pooled | fcw1b
    float* stats  = (float*)d_ws;
    u16*   w2b    = (u16*)((char*)d_ws + 256);
    float* fc1    = (float*)((char*)d_ws + 256);
    u16*   pooled = (u16*)((char*)d_ws + 256 + (size_t)B * 128 * 4);
    u16*   fcw1b  = (u16*)((char*)d_ws + 256 + (size_t)B * 128 * 4 + (size_t)B * 12544 * 2);

    hipMemsetAsync(stats, 0, 32, stream);
    k_stats<<<1024, 256, 0, stream>>>(x, B * 784, stats);
    k_finalize<<<1, 1, 0, stream>>>(gamma, beta, stats);
    k_prepall<<<(128 * 12544 + 255) / 256, 256, 0, stream>>>(w2, fcw1, w2b, fcw1b, 128 * 12544);
    k_conv<<<B, 256, 0, stream>>>(x, w1, b1, w2b, b2, stats, pooled);
    hipMemsetAsync(fc1, 0, (size_t)B * 128 * 4, stream);
    k_fc1<<<dim3(B / 64, 7), 256, 0, stream>>>(pooled, fcw1b, fc1, B);
    k_fc2<<<B / 32, 256, 0, stream>>>(fc1, fcb1, fcw2, fcb2, out, B);
}